// Round 1
// baseline (94.001 us; speedup 1.0000x reference)
//
#include <hip/hip_runtime.h>

#define T_STEPS 256
#define B_SIZE 128
#define N_TAGS 64
#define START_IDX 1
#define END_IDX 2

__device__ __forceinline__ float fexp2(float x) {
    float r; asm("v_exp_f32 %0, %1" : "=v"(r) : "v"(x)); return r;
}
__device__ __forceinline__ float flog2(float x) {
    float r; asm("v_log_f32 %0, %1" : "=v"(r) : "v"(x)); return r;
}

__launch_bounds__(64, 1)
__global__ void crf_logz_kernel(const float* __restrict__ unary,
                                const float* __restrict__ trans,
                                const int* __restrict__ lengths,
                                float* __restrict__ out) {
    const int b = blockIdx.x;
    const int lane = threadIdx.x;  // 0..63, lane == tag index

    __shared__ __align__(16) float sT[N_TAGS * N_TAGS];
    __shared__ __align__(16) float ws[N_TAGS];

    // Stage trans into LDS with coalesced loads.
    {
        const float4* t4 = (const float4*)trans;
        float4* s4 = (float4*)sT;
#pragma unroll
        for (int k = 0; k < 16; ++k) s4[k * 64 + lane] = t4[k * 64 + lane];
    }
    __syncthreads();

    const float K   = 1.4426950408889634f;   // log2(e)
    const float LN2 = 0.6931471805599453f;

    // Lane `to` = lane holds E[to][fr] = exp(trans[to][fr]) in 64 registers.
    float E[64];
    {
        const float4* r4 = (const float4*)(sT + lane * 64);
#pragma unroll
        for (int f = 0; f < 16; ++f) {
            float4 v = r4[f];
            E[4 * f + 0] = fexp2(v.x * K);
            E[4 * f + 1] = fexp2(v.y * K);
            E[4 * f + 2] = fexp2(v.z * K);
            E[4 * f + 3] = fexp2(v.w * K);
        }
    }
    const float tStart = sT[lane * 64 + START_IDX];   // trans[to=lane][START]
    const float tEnd   = sT[END_IDX * 64 + lane];     // trans[END][fr=lane]

    const int len = lengths[b];
    const int off = b * N_TAGS + lane;
    const int BN  = B_SIZE * N_TAGS;

    // t = 0 closed form: exp(-10000) underflows to exactly 0, so
    // alpha0[to] = unary[0,b,to] + trans[to][START].
    float beta = unary[off] + tStart;   // alpha = beta + C
    float C = 0.0f;

    float u_next = (len > 1) ? unary[BN + off] : 0.0f;

    for (int t = 1; t < len; ++t) {
        float u_t = u_next;
        u_next = (t + 1 < len) ? unary[(size_t)(t + 1) * BN + off] : 0.0f;

        // Wave-uniform pivot from lane 0 (spread across tags is bounded ~±12).
        float pivot = __uint_as_float(
            __builtin_amdgcn_readlane(__float_as_uint(beta), 0));
        float w = fexp2((beta - pivot) * K);
        ws[lane] = w;
        __syncthreads();

        float acc0 = 0.f, acc1 = 0.f, acc2 = 0.f, acc3 = 0.f;
#pragma unroll
        for (int f = 0; f < 64; f += 4) {
            float4 wv = *(const float4*)(&ws[f]);   // broadcast read
            acc0 = fmaf(E[f + 0], wv.x, acc0);
            acc1 = fmaf(E[f + 1], wv.y, acc1);
            acc2 = fmaf(E[f + 2], wv.z, acc2);
            acc3 = fmaf(E[f + 3], wv.w, acc3);
        }
        float dot = (acc0 + acc1) + (acc2 + acc3);
        C += pivot;
        beta = u_t + LN2 * flog2(dot);
        __syncthreads();   // protect ws against next iteration's write
    }

    // Terminal: out[b] = C + log(sum_fr exp(beta[fr] + trans[END][fr])).
    // |beta + tEnd| is bounded (~±45 worst case), safe without a pivot.
    float v = fexp2((beta + tEnd) * K);
#pragma unroll
    for (int m = 1; m < 64; m <<= 1) v += __shfl_xor(v, m, 64);
    if (lane == 0) out[b] = C + LN2 * flog2(v);
}

extern "C" void kernel_launch(void* const* d_in, const int* in_sizes, int n_in,
                              void* d_out, int out_size, void* d_ws, size_t ws_size,
                              hipStream_t stream) {
    const float* unary   = (const float*)d_in[0];
    const float* trans   = (const float*)d_in[1];
    const int*   lengths = (const int*)d_in[2];
    float* out = (float*)d_out;

    hipLaunchKernelGGL(crf_logz_kernel, dim3(B_SIZE), dim3(64), 0, stream,
                       unary, trans, lengths, out);
}

// Round 2
// 72.074 us; speedup vs baseline: 1.3042x; 1.3042x over previous
//
#include <hip/hip_runtime.h>

#define T_STEPS 256
#define B_SIZE 128
#define N_TAGS 64
#define START_IDX 1
#define END_IDX 2

__device__ __forceinline__ float fexp2(float x) {
    float r; asm("v_exp_f32 %0, %1" : "=v"(r) : "v"(x)); return r;
}
__device__ __forceinline__ float flog2(float x) {
    float r; asm("v_log_f32 %0, %1" : "=v"(r) : "v"(x)); return r;
}
__device__ __forceinline__ float bcast(float x, int l) {
    return __uint_as_float(__builtin_amdgcn_readlane(__float_as_uint(x), l));
}

__launch_bounds__(64, 1)
__global__ void crf_logz_kernel(const float* __restrict__ unary,
                                const float* __restrict__ trans,
                                const int* __restrict__ lengths,
                                float* __restrict__ out) {
    const int b = blockIdx.x;
    const int lane = threadIdx.x;  // 0..63, lane == tag index

    __shared__ __align__(16) float sT[N_TAGS * N_TAGS];

    // One-time: stage trans into LDS with coalesced loads.
    {
        const float4* t4 = (const float4*)trans;
        float4* s4 = (float4*)sT;
#pragma unroll
        for (int k = 0; k < 16; ++k) s4[k * 64 + lane] = t4[k * 64 + lane];
    }
    __syncthreads();  // once, outside the loop

    const float K   = 1.4426950408889634f;   // log2(e)
    const float LN2 = 0.6931471805599453f;

    // Lane `to` holds E[to][fr] = exp(trans[to][fr]) in 64 registers.
    float E[64];
    {
        const float4* r4 = (const float4*)(sT + lane * 64);
#pragma unroll
        for (int f = 0; f < 16; ++f) {
            float4 v = r4[f];
            E[4 * f + 0] = fexp2(v.x * K);
            E[4 * f + 1] = fexp2(v.y * K);
            E[4 * f + 2] = fexp2(v.z * K);
            E[4 * f + 3] = fexp2(v.w * K);
        }
    }
    const float tStart = sT[lane * 64 + START_IDX];   // trans[to=lane][START]
    const float tEnd   = sT[END_IDX * 64 + lane];     // trans[END][fr=lane]

    const int len = lengths[b];
    const int off = b * N_TAGS + lane;
    const int BN  = B_SIZE * N_TAGS;
    const int tmax = len - 1;  // last valid timestep index

    // t = 0 closed form: exp(-10000) underflows to exactly 0, so
    // alpha0[to] = unary[0,b,to] + trans[to][START].
    float beta = unary[off] + tStart;   // alpha = beta + C
    float C = 0.0f;

    // Branchless depth-2 prefetch ring (clamped index; loads always valid).
    float u_buf0 = unary[(size_t)min(1, tmax) * BN + off];
    float u_buf1 = unary[(size_t)min(2, tmax) * BN + off];

#pragma unroll 2
    for (int t = 1; t < len; ++t) {
        float u_t = u_buf0;
        u_buf0 = u_buf1;
        u_buf1 = unary[(size_t)min(t + 2, tmax) * BN + off];

        // Wave-uniform pivot from lane 0 (spread across tags is bounded ~±12).
        float pivot = bcast(beta, 0);
        float w = fexp2((beta - pivot) * K);

        float acc0 = 0.f, acc1 = 0.f, acc2 = 0.f, acc3 = 0.f;
#pragma unroll
        for (int f = 0; f < 64; f += 4) {
            float w0 = bcast(w, f + 0);
            float w1 = bcast(w, f + 1);
            float w2 = bcast(w, f + 2);
            float w3 = bcast(w, f + 3);
            acc0 = fmaf(E[f + 0], w0, acc0);
            acc1 = fmaf(E[f + 1], w1, acc1);
            acc2 = fmaf(E[f + 2], w2, acc2);
            acc3 = fmaf(E[f + 3], w3, acc3);
        }
        float dot = (acc0 + acc1) + (acc2 + acc3);
        C += pivot;
        beta = u_t + LN2 * flog2(dot);
    }

    // Terminal: out[b] = C + log(sum_fr exp(beta[fr] + trans[END][fr])).
    float v = fexp2((beta + tEnd) * K);
#pragma unroll
    for (int m = 1; m < 64; m <<= 1) v += __shfl_xor(v, m, 64);
    if (lane == 0) out[b] = C + LN2 * flog2(v);
}

extern "C" void kernel_launch(void* const* d_in, const int* in_sizes, int n_in,
                              void* d_out, int out_size, void* d_ws, size_t ws_size,
                              hipStream_t stream) {
    const float* unary   = (const float*)d_in[0];
    const float* trans   = (const float*)d_in[1];
    const int*   lengths = (const int*)d_in[2];
    float* out = (float*)d_out;

    hipLaunchKernelGGL(crf_logz_kernel, dim3(B_SIZE), dim3(64), 0, stream,
                       unary, trans, lengths, out);
}